// Round 6
// baseline (67.054 us; speedup 1.0000x reference)
//
#include <hip/hip_runtime.h>

// Depthwise 3x3 ones-kernel conv (overlap-sum), zero-padded, stride 1.
// x: (64, 512, 40, 40) fp32 -> out: same shape.
//
// R6: persistent grid-stride blocks (2048 = 8/CU), 16 planes each.
// Per plane: stage->bar->hsum->bar->(prefetch next plane)->vsum+nt-store.
// Prefetched loads are consumed before the next __syncthreads, so the
// compiler's vmcnt drain at barriers never stalls on them; each block
// pays the cold load-latency chain once instead of per-plane.

#define NV 400            // float4 per 40x40 plane
#define ROW4 10           // float4 per row
#define NBLOCKS 2048      // 8 blocks/CU * 256 CU

typedef float f32x4 __attribute__((ext_vector_type(4)));

__device__ __forceinline__ float4 hsum4(const float4 c, float lf, float rt) {
    float4 h;
    h.x = lf  + c.x + c.y;
    h.y = c.x + c.y + c.z;
    h.z = c.y + c.z + c.w;
    h.w = c.z + c.w + rt;
    return h;
}

__device__ __forceinline__ void nt_store4(float4* p, const float4 v) {
    f32x4 nv;
    nv.x = v.x; nv.y = v.y; nv.z = v.z; nv.w = v.w;
    __builtin_nontemporal_store(nv, reinterpret_cast<f32x4*>(p));
}

__global__ __launch_bounds__(256) void overlap_sum_3x3(
    const float* __restrict__ in, float* __restrict__ out, int n_planes)
{
    __shared__ float4 s_a[NV];
    __shared__ float4 s_h[NV];

    const int t   = threadIdx.x;
    const bool two = (t < NV - 256);      // threads 0..143 own a 2nd vec4
    const int x40 = t % ROW4;
    const int x41 = (t + 256) % ROW4;

    int p = blockIdx.x;
    if (p >= n_planes) return;

    float4 v0, v1;
    {
        const float4* __restrict__ src =
            reinterpret_cast<const float4*>(in) + (size_t)p * NV;
        v0 = src[t];
        if (two) v1 = src[t + 256];
    }

    while (true) {
        // ---- stage plane into LDS ----
        s_a[t] = v0;
        if (two) s_a[t + 256] = v1;
        __syncthreads();

        // ---- horizontal 3-sum (center from regs) ----
        float lf0 = (x40 > 0)        ? s_a[t - 1].w : 0.0f;
        float rt0 = (x40 < ROW4 - 1) ? s_a[t + 1].x : 0.0f;
        float4 h0 = hsum4(v0, lf0, rt0);
        s_h[t] = h0;

        float4 h1;
        if (two) {
            float lf1 = (x41 > 0)        ? s_a[t + 255].w : 0.0f;
            float rt1 = (x41 < ROW4 - 1) ? s_a[t + 257].x : 0.0f;
            h1 = hsum4(v1, lf1, rt1);
            s_h[t + 256] = h1;
        }
        __syncthreads();

        // ---- prefetch next plane (latency hides under vsum + store) ----
        const int pn = p + NBLOCKS;
        const bool more = (pn < n_planes);
        float4 n0, n1;
        if (more) {
            const float4* __restrict__ srcn =
                reinterpret_cast<const float4*>(in) + (size_t)pn * NV;
            n0 = srcn[t];
            if (two) n1 = srcn[t + 256];
        }

        // ---- vertical 3-sum (center from regs) + nt store ----
        float4* __restrict__ dst =
            reinterpret_cast<float4*>(out) + (size_t)p * NV;
        {
            float4 o = h0;
            if (t >= ROW4) {                 // row above exists
                const float4 u = s_h[t - ROW4];
                o.x += u.x; o.y += u.y; o.z += u.z; o.w += u.w;
            }
            const float4 d = s_h[t + ROW4];  // t < 256: row below exists
            o.x += d.x; o.y += d.y; o.z += d.z; o.w += d.w;
            nt_store4(&dst[t], o);
        }
        if (two) {
            const int j = t + 256;           // row above always exists
            float4 o = h1;
            const float4 u = s_h[j - ROW4];
            o.x += u.x; o.y += u.y; o.z += u.z; o.w += u.w;
            if (j < NV - ROW4) {             // row below exists
                const float4 d = s_h[j + ROW4];
                o.x += d.x; o.y += d.y; o.z += d.z; o.w += d.w;
            }
            nt_store4(&dst[j], o);
        }

        if (!more) break;
        p = pn;
        v0 = n0;
        if (two) v1 = n1;
        // next s_a write conflicts with nothing pending: hsum's s_a reads
        // completed before bar B; s_h reads of this iter finish before the
        // next bar A, after which s_h is rewritten. 2 barriers/plane total.
    }
}

extern "C" void kernel_launch(void* const* d_in, const int* in_sizes, int n_in,
                              void* d_out, int out_size, void* d_ws, size_t ws_size,
                              hipStream_t stream) {
    const float* x = (const float*)d_in[0];
    float* out = (float*)d_out;
    const int n_planes = in_sizes[0] / (NV * 4);   // 32768 planes
    const int grid = (n_planes < NBLOCKS) ? n_planes : NBLOCKS;
    overlap_sum_3x3<<<grid, 256, 0, stream>>>(x, out, n_planes);
}

// Round 7
// 63.518 us; speedup vs baseline: 1.0557x; 1.0557x over previous
//
#include <hip/hip_runtime.h>

// Depthwise 3x3 ones-kernel conv (overlap-sum), zero-padded, stride 1.
// x: (64, 512, 40, 40) fp32 -> out: same shape.
//
// R7 = revert to R5 (63.6 us): one block per 40x40 plane, separable
// stencil, all-float4 LDS traffic, 2 barriers, nontemporal output stores
// (write-once stream does not evict the L3-resident input).
// R6's persistent+prefetch variant regressed (67.1 us): prefetch window
// (vsum+store) << HBM latency, and block-level TLP already covered it.

#define NV 400            // float4 per 40x40 plane
#define ROW4 10           // float4 per row

typedef float f32x4 __attribute__((ext_vector_type(4)));

__device__ __forceinline__ float4 hsum4(const float4 c, float lf, float rt) {
    float4 h;
    h.x = lf  + c.x + c.y;
    h.y = c.x + c.y + c.z;
    h.z = c.y + c.z + c.w;
    h.w = c.z + c.w + rt;
    return h;
}

__device__ __forceinline__ void nt_store4(float4* p, const float4 v) {
    f32x4 nv;
    nv.x = v.x; nv.y = v.y; nv.z = v.z; nv.w = v.w;
    __builtin_nontemporal_store(nv, reinterpret_cast<f32x4*>(p));
}

__global__ __launch_bounds__(256) void overlap_sum_3x3(
    const float* __restrict__ in, float* __restrict__ out)
{
    __shared__ float4 s_a[NV];
    __shared__ float4 s_h[NV];

    const int t = threadIdx.x;
    const size_t po = (size_t)blockIdx.x * NV;
    const float4* __restrict__ src = reinterpret_cast<const float4*>(in) + po;
    float4*       __restrict__ dst = reinterpret_cast<float4*>(out) + po;

    // ---- stage plane into LDS, keep values in regs ----
    const bool two = (t < NV - 256);      // threads 0..143 own a 2nd vec4
    float4 v0 = src[t];
    float4 v1;
    s_a[t] = v0;
    if (two) { v1 = src[t + 256]; s_a[t + 256] = v1; }
    __syncthreads();

    // ---- horizontal 3-sum (center from regs, edges via b128 neighbors) ----
    const int x40 = t % ROW4;
    float lf0 = (x40 > 0)        ? s_a[t - 1].w : 0.0f;
    float rt0 = (x40 < ROW4 - 1) ? s_a[t + 1].x : 0.0f;
    float4 h0 = hsum4(v0, lf0, rt0);
    s_h[t] = h0;

    float4 h1;
    if (two) {
        const int j  = t + 256;
        const int x41 = j % ROW4;
        float lf1 = (x41 > 0)        ? s_a[j - 1].w : 0.0f;
        float rt1 = (x41 < ROW4 - 1) ? s_a[j + 1].x : 0.0f;
        h1 = hsum4(v1, lf1, rt1);
        s_h[j] = h1;
    }
    __syncthreads();

    // ---- vertical 3-sum (center from regs) + nt store ----
    {
        float4 o = h0;
        if (t >= ROW4) {                 // row above exists
            const float4 u = s_h[t - ROW4];
            o.x += u.x; o.y += u.y; o.z += u.z; o.w += u.w;
        }
        const float4 d = s_h[t + ROW4];  // t < 256 <= NV-ROW4: row below exists
        o.x += d.x; o.y += d.y; o.z += d.z; o.w += d.w;
        nt_store4(&dst[t], o);
    }
    if (two) {
        const int j = t + 256;           // j in [256,400): row above always exists
        float4 o = h1;
        const float4 u = s_h[j - ROW4];
        o.x += u.x; o.y += u.y; o.z += u.z; o.w += u.w;
        if (j < NV - ROW4) {             // row below exists
            const float4 d = s_h[j + ROW4];
            o.x += d.x; o.y += d.y; o.z += d.z; o.w += d.w;
        }
        nt_store4(&dst[j], o);
    }
}

extern "C" void kernel_launch(void* const* d_in, const int* in_sizes, int n_in,
                              void* d_out, int out_size, void* d_ws, size_t ws_size,
                              hipStream_t stream) {
    const float* x = (const float*)d_in[0];
    float* out = (float*)d_out;
    const int n_planes = in_sizes[0] / (NV * 4);   // 32768 planes
    overlap_sum_3x3<<<n_planes, 256, 0, stream>>>(x, out);
}